// Round 5
// baseline (448.934 us; speedup 1.0000x reference)
//
#include <hip/hip_runtime.h>
#include <math.h>
#include <stdint.h>

#define ALPHA 0.1f
#define EPS 1e-7f

constexpr int D = 65;                  // 1 time-like + 64 space dims
constexpr int A = 16;                  // anchors
constexpr int RPW = 64;                // rows per tile (one wave, one thread/row)
constexpr int TILE_FLOATS = RPW * D;   // 4160 floats = 16640 B

// ---------------------------------------------------------------------------
// async global->LDS DMA helpers (gfx950: size 4 or 16). LDS dest is
// wave-uniform base + lane*size; global addr is per-lane.
// ---------------------------------------------------------------------------
__device__ __forceinline__ void async_cp16(const float* g, float* l) {
    __builtin_amdgcn_global_load_lds(
        (const __attribute__((address_space(1))) uint32_t*)(uintptr_t)g,
        (__attribute__((address_space(3))) uint32_t*)(uint32_t)(uintptr_t)l,
        16, 0, 0);
}
__device__ __forceinline__ void async_cp4(const float* g, float* l) {
    __builtin_amdgcn_global_load_lds(
        (const __attribute__((address_space(1))) uint32_t*)(uintptr_t)g,
        (__attribute__((address_space(3))) uint32_t*)(uint32_t)(uintptr_t)l,
        4, 0, 0);
}

// ---------------------------------------------------------------------------
// Prep: project anchors, write to ws:
//   ws[0 .. A*D) : transposed aT[j*A + a] — the ONLY layout the main kernel
//                  uses now (uniform b128 broadcast reads + na gather).
// ---------------------------------------------------------------------------
__global__ void prep_anchors(const float* __restrict__ anchors,
                             float* __restrict__ ws) {
    __shared__ float s_a[A * D];
    int tid = threadIdx.x;
    for (int i = tid; i < A * D; i += blockDim.x) s_a[i] = anchors[i];
    __syncthreads();
    if (tid < A) {
        float s = 0.f;
        for (int j = 1; j < D; ++j) {
            float v = s_a[tid * D + j];
            s = fmaf(v, v, s);
        }
        s_a[tid * D] = sqrtf(1.f + s);
    }
    __syncthreads();
    for (int i = tid; i < A * D; i += blockDim.x) {
        int a = i / D, j = i % D;
        ws[j * A + a] = s_a[i];    // transposed [j][a]
    }
}

// ---------------------------------------------------------------------------
// Per-row math, anchors read from LDS (aL = [65][16] transposed):
//  - inner products: wave-uniform float4 reads of aL row j -> ds_read_b128
//    broadcast (LDS pipe, lgkm-batched; NO scalar s_load storm — rounds 0-4
//    all stalled ~64% per wave on 1040 s_loads/tile through the SMEM path)
//  - na gather: aL[j*16 + bidx], divergent bidx<16 at fixed j -> 16 distinct
//    banks, conflict-free
//  - branch-free transcendentals: acosh(z)=log(z+sqrt(z^2-1)); cosh/sinhc
//    from one expf + reciprocal (tolerance-safe: vn small, z>=1+eps)
// Semantics (argmin strict <, first-index ties; EPS clamps) unchanged.
// ---------------------------------------------------------------------------
__device__ __forceinline__ void row_math_lds(const float xr[D],
                                             const float* __restrict__ aL,
                                             float* __restrict__ orow) {
    const float4* a4 = (const float4*)aL;    // 65 rows x 4 float4
    float acc[A];
    {
        float4 b0 = a4[0], b1 = a4[1], b2 = a4[2], b3 = a4[3];
        const float x0 = -xr[0];
        acc[0]  = x0 * b0.x; acc[1]  = x0 * b0.y; acc[2]  = x0 * b0.z; acc[3]  = x0 * b0.w;
        acc[4]  = x0 * b1.x; acc[5]  = x0 * b1.y; acc[6]  = x0 * b1.z; acc[7]  = x0 * b1.w;
        acc[8]  = x0 * b2.x; acc[9]  = x0 * b2.y; acc[10] = x0 * b2.z; acc[11] = x0 * b2.w;
        acc[12] = x0 * b3.x; acc[13] = x0 * b3.y; acc[14] = x0 * b3.z; acc[15] = x0 * b3.w;
    }
#pragma unroll
    for (int j = 1; j < D; ++j) {
        float4 b0 = a4[j * 4 + 0], b1 = a4[j * 4 + 1];
        float4 b2 = a4[j * 4 + 2], b3 = a4[j * 4 + 3];
        const float xj = xr[j];
        acc[0]  = fmaf(xj, b0.x, acc[0]);  acc[1]  = fmaf(xj, b0.y, acc[1]);
        acc[2]  = fmaf(xj, b0.z, acc[2]);  acc[3]  = fmaf(xj, b0.w, acc[3]);
        acc[4]  = fmaf(xj, b1.x, acc[4]);  acc[5]  = fmaf(xj, b1.y, acc[5]);
        acc[6]  = fmaf(xj, b1.z, acc[6]);  acc[7]  = fmaf(xj, b1.w, acc[7]);
        acc[8]  = fmaf(xj, b2.x, acc[8]);  acc[9]  = fmaf(xj, b2.y, acc[9]);
        acc[10] = fmaf(xj, b2.z, acc[10]); acc[11] = fmaf(xj, b2.w, acc[11]);
        acc[12] = fmaf(xj, b3.x, acc[12]); acc[13] = fmaf(xj, b3.y, acc[13]);
        acc[14] = fmaf(xj, b3.z, acc[14]); acc[15] = fmaf(xj, b3.w, acc[15]);
    }

    // argmin of acosh(max(-inner,1+eps)); strict < = first-index ties
    const float onePlusEps = 1.0f + EPS;
    float bestZ = fmaxf(-acc[0], onePlusEps);
    float xy = acc[0];
    int bidx = 0;
#pragma unroll
    for (int a = 1; a < A; ++a) {
        float z = fmaxf(-acc[a], onePlusEps);
        if (z < bestZ) { bestZ = z; bidx = a; xy = acc[a]; }
    }
    // acosh(z) = log(z + sqrt(z^2-1)), branch-free (z >= 1+eps)
    const float d = logf(bestZ + sqrtf(fmaf(bestZ, bestZ, -1.0f)));

    // na gather from the transposed array: aL[j*16 + bidx]
    float uu;
    {
        float u0 = fmaf(xy, xr[0], aL[bidx]);
        uu = -u0 * u0;
    }
#pragma unroll
    for (int j = 1; j < D; ++j) {
        float uj = fmaf(xy, xr[j], aL[j * A + bidx]);
        uu = fmaf(uj, uj, uu);
    }
    const float unorm = sqrtf(fmaxf(uu, EPS));
    const float c = ALPHA * d / unorm;
    const float vv = c * c * uu;
    const float vn = sqrtf(fmaxf(vv, EPS * EPS));
    // cosh/sinhc from one expf (vn in ~[1e-7, few]; no overflow)
    const float e  = __expf(vn) ; // fast exp: |rel err| ~1e-6, well within tol
    const float ei = 1.0f / e;
    const float ch = 0.5f * (e + ei);
    const float sinhc = (vn > EPS) ? (0.5f * (e - ei) / vn) : 1.0f;
    const float sc = sinhc * c;
    const float k1 = fmaf(sc, xy, ch);    // ch + sc*xy
#pragma unroll
    for (int j = 0; j < D; ++j)
        orow[j] = fmaf(k1, xr[j], sc * aL[j * A + bidx]);
}

// ---------------------------------------------------------------------------
// Main: ONE-SHOT single-wave blocks (round-4 structure, best measured),
// one 64-row tile per block, zero barriers. LDS 20800 B -> 7 blocks/CU.
// Change vs round 4: anchor data path moved off the scalar/SMEM pipe onto
// LDS broadcast reads (see row_math_lds).
// ---------------------------------------------------------------------------
__global__ __launch_bounds__(64, 1) void
homeo_kernel(const float* __restrict__ x,
             const float* __restrict__ aT,    // [D][A] transposed, projected
             float* __restrict__ out, int B) {
    __shared__ float buf[TILE_FLOATS];        // 16640 B
    __shared__ float aL[A * D];               // 4160 B transposed [j][a]

    const int lane = threadIdx.x;             // 0..63, one wave per block
    const long t = blockIdx.x;                // this block's tile
    const long rowStart = t * RPW;
    const int nRows = (int)min((long)RPW, (long)B - rowStart);
    const bool full = (nRows == RPW);

    // ---- issue this tile's DMA first: bytes start flowing immediately ----
    if (full) {
        const float* g = x + rowStart * (long)D;
#pragma unroll
        for (int c = 0; c < 16; ++c)
            async_cp16(g + c * 256 + lane * 4, buf + c * 256);
        async_cp4(g + 16 * 256 + lane, buf + 16 * 256);
    }

    // ---- anchors -> LDS (L2-hot, overlaps DMA flight; single wave so
    // compiler-inserted lgkmcnt orders ds_write -> ds_read, no barrier) ----
    for (int i = lane; i < A * D; i += 64) aL[i] = aT[i];

    if (full) {
        // compiler inserts the (required) vmcnt wait before these ds_reads.
        // bank = (lane*65 + j) % 32 = (lane + j) % 32 -> 2-way, free
        float xr[D];
#pragma unroll
        for (int j = 0; j < D; ++j) xr[j] = buf[lane * D + j];

        // result written back in place (reads fully consumed into xr)
        row_math_lds(xr, aL, buf + lane * D);

        // wave-local fence: all lanes' LDS writes retired before the
        // cross-lane reads in the coalesced store below
        asm volatile("s_waitcnt lgkmcnt(0)" ::: "memory");

        float4* o4 = (float4*)(out + rowStart * (long)D);
        const float4* l4 = (const float4*)buf;
#pragma unroll
        for (int c2 = 0; c2 < 16; ++c2)
            o4[c2 * 64 + lane] = l4[c2 * 64 + lane];
        out[rowStart * (long)D + 16 * 256 + lane] = buf[16 * 256 + lane];
    } else if (lane < nRows) {
        // partial tile (unused at B=1e6: 15625 full tiles exactly):
        // direct global read/write, no input staging (aL already in LDS)
        const float* xg = x + (rowStart + lane) * (long)D;
        float xr[D];
        for (int j = 0; j < D; ++j) xr[j] = xg[j];
        row_math_lds(xr, aL, out + (rowStart + lane) * (long)D);
    }
}

extern "C" void kernel_launch(void* const* d_in, const int* in_sizes, int n_in,
                              void* d_out, int out_size, void* d_ws, size_t ws_size,
                              hipStream_t stream) {
    const float* hyp = (const float*)d_in[0];
    const float* anchors = (const float*)d_in[1];
    float* out = (float*)d_out;
    float* ws = (float*)d_ws;

    const int B = in_sizes[0] / D;                 // 1,000,000
    const int nTiles = (B + RPW - 1) / RPW;        // 15,625 tiles = grid

    prep_anchors<<<1, 256, 0, stream>>>(anchors, ws);
    homeo_kernel<<<nTiles, 64, 0, stream>>>(hyp, ws, out, B);
}